// Round 1
// baseline (1685.453 us; speedup 1.0000x reference)
//
#include <hip/hip_runtime.h>
#include <hip/hip_bf16.h>
#include <math.h>

// AGDN: 2-layer graph attention. N=100000, E=1600000, IN=128, HID=16, HEADS=4, OUT=64.
#define NN 100000
#define EE 1600000
#define IN_DIM 128
#define HID 16
#define HEADS 4
#define D1 64            // HEADS*HID
#define OUT_DIM 64
#define SLOPE 0.2f

// ---- ordered-uint encoding for float atomicMax (monotone map f32 -> u32) ----
__device__ __forceinline__ unsigned ford(float f) {
    unsigned u = __float_as_uint(f);
    return (u & 0x80000000u) ? ~u : (u | 0x80000000u);
}
__device__ __forceinline__ float funord(unsigned u) {
    return (u & 0x80000000u) ? __uint_as_float(u ^ 0x80000000u) : __uint_as_float(~u);
}

__device__ __forceinline__ float leaky(float v) { return v > 0.f ? v : SLOPE * v; }

// ================= Layer 1 node phase =================
// 8 nodes per block, 128 threads. t<64: x_lin1 col t. t>=64: residual col t-64.
#define NPB1 8
__global__ void node1_kernel(const float* __restrict__ x,
                             const float* __restrict__ W1,
                             const float* __restrict__ resW,
                             const float* __restrict__ attl,
                             const float* __restrict__ attr,
                             const float* __restrict__ b1,
                             float* __restrict__ xlin1,
                             float* __restrict__ acc1,
                             float* __restrict__ al1,
                             float* __restrict__ ar1,
                             unsigned* __restrict__ m1,
                             float* __restrict__ s1) {
    int base = blockIdx.x * NPB1;
    int t = threadIdx.x;  // 0..127
    __shared__ float xs[NPB1][IN_DIM];
    __shared__ float xl[NPB1][D1];

    for (int i = t; i < NPB1 * IN_DIM; i += 128) {
        int n = i >> 7, k = i & 127;
        xs[n][k] = x[(size_t)(base + n) * IN_DIM + k];
    }
    __syncthreads();

    int col = t & 63;
    const float* Wp = (t < 64) ? W1 : resW;
    float acc[NPB1];
#pragma unroll
    for (int n = 0; n < NPB1; n++) acc[n] = 0.f;
    for (int k = 0; k < IN_DIM; k++) {
        float w = Wp[k * D1 + col];
#pragma unroll
        for (int n = 0; n < NPB1; n++) acc[n] += xs[n][k] * w;
    }
    if (t < 64) {
#pragma unroll
        for (int n = 0; n < NPB1; n++) {
            xlin1[(size_t)(base + n) * D1 + col] = acc[n];
            xl[n][col] = acc[n];
        }
    } else {
        float bv = b1[col];
#pragma unroll
        for (int n = 0; n < NPB1; n++) {
            acc1[(size_t)(base + n) * D1 + col] = acc[n] + bv;
        }
    }
    __syncthreads();
    // attention dots: 64 threads -> 8 nodes x (4 heads left + 4 heads right)
    if (t < 64) {
        int n = t >> 3;
        int q = t & 7;
        int h = q & 3;
        const float* att = (q < 4) ? attl : attr;
        float s = 0.f;
#pragma unroll
        for (int c = 0; c < HID; c++) s += xl[n][h * HID + c] * att[h * HID + c];
        if (q < 4) al1[(base + n) * HEADS + h] = s;
        else       ar1[(base + n) * HEADS + h] = s;
    }
    // init segment max/sum
    if (t < NPB1 * HEADS) {
        int n = t >> 2, h = t & 3;
        m1[(base + n) * HEADS + h] = 0u;   // ford of -inf-ish floor (smallest key)
        s1[(base + n) * HEADS + h] = 0.f;
    }
}

// ================= Layer 1 edge phase =================
__global__ void edge_max1(const int* __restrict__ src, const int* __restrict__ dst,
                          const float* __restrict__ al, const float* __restrict__ ar,
                          unsigned* __restrict__ m1) {
    int e = blockIdx.x * blockDim.x + threadIdx.x;
    if (e >= EE) return;
    int s = src[e], d = dst[e];
#pragma unroll
    for (int h = 0; h < HEADS; h++) {
        float l = leaky(al[s * HEADS + h] + ar[d * HEADS + h]);
        atomicMax(&m1[d * HEADS + h], ford(l));
    }
}

__global__ void edge_sum1(const int* __restrict__ src, const int* __restrict__ dst,
                          const float* __restrict__ al, const float* __restrict__ ar,
                          const unsigned* __restrict__ m1, float* __restrict__ s1) {
    int e = blockIdx.x * blockDim.x + threadIdx.x;
    if (e >= EE) return;
    int s = src[e], d = dst[e];
#pragma unroll
    for (int h = 0; h < HEADS; h++) {
        float l = leaky(al[s * HEADS + h] + ar[d * HEADS + h]);
        float ev = __expf(l - funord(m1[d * HEADS + h]));
        atomicAdd(&s1[d * HEADS + h], ev);
    }
}

// 4 edges per 256-thread block; each 64-lane group handles one edge's 64 channels.
__global__ void edge_msg1(const int* __restrict__ src, const int* __restrict__ dst,
                          const float* __restrict__ al, const float* __restrict__ ar,
                          const unsigned* __restrict__ m1, const float* __restrict__ s1,
                          const float* __restrict__ xlin1, float* __restrict__ acc1) {
    int e = blockIdx.x * 4 + (threadIdx.x >> 6);
    if (e >= EE) return;
    int lane = threadIdx.x & 63;
    int s = src[e], d = dst[e];
    int h = lane >> 4;  // 16 channels per head
    float l = leaky(al[s * HEADS + h] + ar[d * HEADS + h]);
    float alpha = __expf(l - funord(m1[d * HEADS + h])) / (s1[d * HEADS + h] + 1e-16f);
    float v = xlin1[(size_t)s * D1 + lane] * alpha;
    atomicAdd(&acc1[(size_t)d * D1 + lane], v);
}

// ================= ELU =================
__global__ void elu_kernel(float* __restrict__ a, int n) {
    int i = blockIdx.x * blockDim.x + threadIdx.x;
    if (i >= n) return;
    float v = a[i];
    a[i] = v > 0.f ? v : (__expf(v) - 1.f);
}

// ================= Layer 2 node phase =================
// one node per 64-thread block; W2 (16KB) lives in L1.
__global__ void node2_kernel(const float* __restrict__ h,
                             const float* __restrict__ W2,
                             const float* __restrict__ attl2,
                             const float* __restrict__ attr2,
                             const float* __restrict__ b2,
                             float* __restrict__ xlin2,
                             float* __restrict__ out,
                             float* __restrict__ al2,
                             float* __restrict__ ar2,
                             unsigned* __restrict__ m2,
                             float* __restrict__ s2) {
    int node = blockIdx.x;
    int t = threadIdx.x;  // 0..63
    __shared__ float hs[D1];
    hs[t] = h[(size_t)node * D1 + t];
    __syncthreads();
    float acc = 0.f;
    for (int k = 0; k < D1; k++) acc += hs[k] * W2[k * OUT_DIM + t];
    xlin2[(size_t)node * OUT_DIM + t] = acc;
    out[(size_t)node * OUT_DIM + t] = acc + b2[t];
    float pl = acc * attl2[t];
    float pr = acc * attr2[t];
#pragma unroll
    for (int off = 32; off > 0; off >>= 1) {
        pl += __shfl_down(pl, off, 64);
        pr += __shfl_down(pr, off, 64);
    }
    if (t == 0) {
        al2[node] = pl;
        ar2[node] = pr;
        m2[node] = 0u;
        s2[node] = 0.f;
    }
}

// ================= Layer 2 edge phase =================
__global__ void edge_max2(const int* __restrict__ src, const int* __restrict__ dst,
                          const float* __restrict__ al, const float* __restrict__ ar,
                          unsigned* __restrict__ m2) {
    int e = blockIdx.x * blockDim.x + threadIdx.x;
    if (e >= EE) return;
    float l = leaky(al[src[e]] + ar[dst[e]]);
    atomicMax(&m2[dst[e]], ford(l));
}

__global__ void edge_sum2(const int* __restrict__ src, const int* __restrict__ dst,
                          const float* __restrict__ al, const float* __restrict__ ar,
                          const unsigned* __restrict__ m2, float* __restrict__ s2) {
    int e = blockIdx.x * blockDim.x + threadIdx.x;
    if (e >= EE) return;
    int d = dst[e];
    float l = leaky(al[src[e]] + ar[d]);
    atomicAdd(&s2[d], __expf(l - funord(m2[d])));
}

__global__ void edge_msg2(const int* __restrict__ src, const int* __restrict__ dst,
                          const float* __restrict__ al, const float* __restrict__ ar,
                          const unsigned* __restrict__ m2, const float* __restrict__ s2,
                          const float* __restrict__ xlin2, float* __restrict__ out) {
    int e = blockIdx.x * 4 + (threadIdx.x >> 6);
    if (e >= EE) return;
    int lane = threadIdx.x & 63;
    int s = src[e], d = dst[e];
    float l = leaky(al[s] + ar[d]);
    float alpha = __expf(l - funord(m2[d])) / (s2[d] + 1e-16f);
    float v = xlin2[(size_t)s * OUT_DIM + lane] * alpha;
    atomicAdd(&out[(size_t)d * OUT_DIM + lane], v);
}

extern "C" void kernel_launch(void* const* d_in, const int* in_sizes, int n_in,
                              void* d_out, int out_size, void* d_ws, size_t ws_size,
                              hipStream_t stream) {
    const float* x     = (const float*)d_in[0];
    const int*   eidx  = (const int*)d_in[1];
    const float* W1    = (const float*)d_in[2];
    const float* attl1 = (const float*)d_in[3];
    const float* attr1 = (const float*)d_in[4];
    const float* resW1 = (const float*)d_in[5];
    const float* b1    = (const float*)d_in[6];
    const float* W2    = (const float*)d_in[7];
    const float* attl2 = (const float*)d_in[8];
    const float* attr2 = (const float*)d_in[9];
    const float* b2    = (const float*)d_in[10];

    const int* src = eidx;
    const int* dst = eidx + EE;

    // workspace layout (floats)
    float* ws = (float*)d_ws;
    float*    xlin1 = ws;                       // N*64
    float*    acc1  = xlin1 + (size_t)NN * D1;  // N*64 (becomes h after elu)
    float*    xlin2 = acc1  + (size_t)NN * D1;  // N*64
    float*    al1   = xlin2 + (size_t)NN * D1;  // N*4
    float*    ar1   = al1 + (size_t)NN * HEADS;
    unsigned* m1    = (unsigned*)(ar1 + (size_t)NN * HEADS);
    float*    s1    = (float*)(m1 + (size_t)NN * HEADS);
    float*    al2   = s1 + (size_t)NN * HEADS;  // N
    float*    ar2   = al2 + NN;
    unsigned* m2    = (unsigned*)(ar2 + NN);
    float*    s2    = (float*)(m2 + NN);

    float* out = (float*)d_out;

    // layer 1
    node1_kernel<<<NN / NPB1, 128, 0, stream>>>(x, W1, resW1, attl1, attr1, b1,
                                                xlin1, acc1, al1, ar1, m1, s1);
    edge_max1<<<(EE + 255) / 256, 256, 0, stream>>>(src, dst, al1, ar1, m1);
    edge_sum1<<<(EE + 255) / 256, 256, 0, stream>>>(src, dst, al1, ar1, m1, s1);
    edge_msg1<<<(EE + 3) / 4, 256, 0, stream>>>(src, dst, al1, ar1, m1, s1, xlin1, acc1);
    elu_kernel<<<(NN * D1 + 255) / 256, 256, 0, stream>>>(acc1, NN * D1);
    // layer 2
    node2_kernel<<<NN, 64, 0, stream>>>(acc1, W2, attl2, attr2, b2,
                                        xlin2, out, al2, ar2, m2, s2);
    edge_max2<<<(EE + 255) / 256, 256, 0, stream>>>(src, dst, al2, ar2, m2);
    edge_sum2<<<(EE + 255) / 256, 256, 0, stream>>>(src, dst, al2, ar2, m2, s2);
    edge_msg2<<<(EE + 3) / 4, 256, 0, stream>>>(src, dst, al2, ar2, m2, s2, xlin2, out);
}

// Round 2
// 591.473 us; speedup vs baseline: 2.8496x; 2.8496x over previous
//
#include <hip/hip_runtime.h>
#include <hip/hip_bf16.h>
#include <math.h>

// AGDN: 2-layer graph attention. N=100000, E=1600000, IN=128, HID=16, HEADS=4, OUT=64.
// Strategy: build CSR (edges sorted by dst) on device, then one fused
// gather-aggregate kernel per layer (online softmax + message sum, no atomics
// on feature data). One 64-lane wave per dst node.
#define NN 100000
#define EE 1600000
#define IN_DIM 128
#define HID 16
#define HEADS 4
#define D1 64            // HEADS*HID
#define OUT_DIM 64
#define SLOPE 0.2f
#define SCAN_BLOCKS ((NN + 255) / 256)   // 391

__device__ __forceinline__ float leaky(float v) { return v > 0.f ? v : SLOPE * v; }

// ================= Layer 1 node phase =================
// 8 nodes per block, 128 threads. t<64: x_lin1 col t. t>=64: residual col t-64.
#define NPB1 8
__global__ void node1_kernel(const float* __restrict__ x,
                             const float* __restrict__ W1,
                             const float* __restrict__ resW,
                             const float* __restrict__ attl,
                             const float* __restrict__ attr,
                             const float* __restrict__ b1,
                             float* __restrict__ xlin1,
                             float* __restrict__ acc1,
                             float* __restrict__ al1,
                             float* __restrict__ ar1) {
    int base = blockIdx.x * NPB1;
    int t = threadIdx.x;  // 0..127
    __shared__ float xs[NPB1][IN_DIM];
    __shared__ float xl[NPB1][D1];

    for (int i = t; i < NPB1 * IN_DIM; i += 128) {
        int n = i >> 7, k = i & 127;
        xs[n][k] = x[(size_t)(base + n) * IN_DIM + k];
    }
    __syncthreads();

    int col = t & 63;
    const float* Wp = (t < 64) ? W1 : resW;
    float acc[NPB1];
#pragma unroll
    for (int n = 0; n < NPB1; n++) acc[n] = 0.f;
    for (int k = 0; k < IN_DIM; k++) {
        float w = Wp[k * D1 + col];
#pragma unroll
        for (int n = 0; n < NPB1; n++) acc[n] += xs[n][k] * w;
    }
    if (t < 64) {
#pragma unroll
        for (int n = 0; n < NPB1; n++) {
            xlin1[(size_t)(base + n) * D1 + col] = acc[n];
            xl[n][col] = acc[n];
        }
    } else {
        float bv = b1[col];
#pragma unroll
        for (int n = 0; n < NPB1; n++) {
            acc1[(size_t)(base + n) * D1 + col] = acc[n] + bv;
        }
    }
    __syncthreads();
    // attention dots: 64 threads -> 8 nodes x (4 heads left + 4 heads right)
    if (t < 64) {
        int n = t >> 3;
        int q = t & 7;
        int h = q & 3;
        const float* att = (q < 4) ? attl : attr;
        float s = 0.f;
#pragma unroll
        for (int c = 0; c < HID; c++) s += xl[n][h * HID + c] * att[h * HID + c];
        if (q < 4) al1[(base + n) * HEADS + h] = s;
        else       ar1[(base + n) * HEADS + h] = s;
    }
}

// ================= CSR build =================
__global__ void zero_counts(int* __restrict__ counts) {
    int i = blockIdx.x * blockDim.x + threadIdx.x;
    if (i < NN) counts[i] = 0;
}

__global__ void hist_kernel(const int* __restrict__ dst, int* __restrict__ counts) {
    int e = blockIdx.x * blockDim.x + threadIdx.x;
    if (e < EE) atomicAdd(&counts[dst[e]], 1);
}

__global__ void scan_local(const int* __restrict__ counts, int* __restrict__ row_ptr,
                           int* __restrict__ blocksums) {
    __shared__ int tmp[256];
    int i = blockIdx.x * 256 + threadIdx.x;
    int v = (i < NN) ? counts[i] : 0;
    tmp[threadIdx.x] = v;
    __syncthreads();
    for (int off = 1; off < 256; off <<= 1) {
        int t = (threadIdx.x >= off) ? tmp[threadIdx.x - off] : 0;
        __syncthreads();
        tmp[threadIdx.x] += t;
        __syncthreads();
    }
    if (i < NN) row_ptr[i] = tmp[threadIdx.x] - v;  // exclusive
    if (threadIdx.x == 255) blocksums[blockIdx.x] = tmp[255];
}

__global__ void scan_top(int* __restrict__ blocksums) {
    __shared__ int tmp[512];
    int v = (threadIdx.x < SCAN_BLOCKS) ? blocksums[threadIdx.x] : 0;
    tmp[threadIdx.x] = v;
    __syncthreads();
    for (int off = 1; off < 512; off <<= 1) {
        int t = (threadIdx.x >= off) ? tmp[threadIdx.x - off] : 0;
        __syncthreads();
        tmp[threadIdx.x] += t;
        __syncthreads();
    }
    if (threadIdx.x < SCAN_BLOCKS) blocksums[threadIdx.x] = tmp[threadIdx.x] - v;  // exclusive
}

__global__ void scan_add(int* __restrict__ row_ptr, const int* __restrict__ blocksums,
                         int* __restrict__ cursor) {
    int i = blockIdx.x * blockDim.x + threadIdx.x;
    if (i < NN) {
        int r = row_ptr[i] + blocksums[i >> 8];
        row_ptr[i] = r;
        cursor[i] = r;
    }
}

__global__ void scatter_kernel(const int* __restrict__ src, const int* __restrict__ dst,
                               int* __restrict__ cursor, int* __restrict__ sorted_src) {
    int e = blockIdx.x * blockDim.x + threadIdx.x;
    if (e >= EE) return;
    int d = dst[e];
    int p = atomicAdd(&cursor[d], 1);
    sorted_src[p] = src[e];
}

// ================= Fused aggregation, layer 1 (H=4, C=16) =================
// One wave per dst node; 4 waves / 256-thread block.
__global__ __launch_bounds__(256) void agg1_kernel(
        const int* __restrict__ sorted_src, const int* __restrict__ row_ptr,
        const int* __restrict__ counts,
        const float* __restrict__ al1, const float* __restrict__ ar1,
        const float* __restrict__ xlin1, float* __restrict__ acc1) {
    int d = blockIdx.x * 4 + (threadIdx.x >> 6);
    if (d >= NN) return;
    int lane = threadIdx.x & 63;
    int rs = row_ptr[d];
    int deg = counts[d];
    int re = rs + deg;
    float ar0 = ar1[d * 4 + 0], arv1 = ar1[d * 4 + 1];
    float arv2 = ar1[d * 4 + 2], arv3 = ar1[d * 4 + 3];

    // ---- pass 1: edge-parallel online softmax (per-lane, then butterfly) ----
    float m0 = -1e30f, m1 = -1e30f, m2 = -1e30f, m3 = -1e30f;
    float s0 = 0.f, s1 = 0.f, s2 = 0.f, s3 = 0.f;
    int src_reg = 0;
    float l0 = 0.f, l1 = 0.f, l2 = 0.f, l3 = 0.f;
    for (int e = rs + lane; e < re; e += 64) {
        int s = sorted_src[e];
        src_reg = s;
        l0 = leaky(al1[s * 4 + 0] + ar0);
        l1 = leaky(al1[s * 4 + 1] + arv1);
        l2 = leaky(al1[s * 4 + 2] + arv2);
        l3 = leaky(al1[s * 4 + 3] + arv3);
        float mn;
        mn = fmaxf(m0, l0); s0 = s0 * __expf(m0 - mn) + __expf(l0 - mn); m0 = mn;
        mn = fmaxf(m1, l1); s1 = s1 * __expf(m1 - mn) + __expf(l1 - mn); m1 = mn;
        mn = fmaxf(m2, l2); s2 = s2 * __expf(m2 - mn) + __expf(l2 - mn); m2 = mn;
        mn = fmaxf(m3, l3); s3 = s3 * __expf(m3 - mn) + __expf(l3 - mn); m3 = mn;
    }
#pragma unroll
    for (int off = 1; off < 64; off <<= 1) {
        float om, os, mn;
        om = __shfl_xor(m0, off, 64); os = __shfl_xor(s0, off, 64);
        mn = fmaxf(m0, om); s0 = s0 * __expf(m0 - mn) + os * __expf(om - mn); m0 = mn;
        om = __shfl_xor(m1, off, 64); os = __shfl_xor(s1, off, 64);
        mn = fmaxf(m1, om); s1 = s1 * __expf(m1 - mn) + os * __expf(om - mn); m1 = mn;
        om = __shfl_xor(m2, off, 64); os = __shfl_xor(s2, off, 64);
        mn = fmaxf(m2, om); s2 = s2 * __expf(m2 - mn) + os * __expf(om - mn); m2 = mn;
        om = __shfl_xor(m3, off, 64); os = __shfl_xor(s3, off, 64);
        mn = fmaxf(m3, om); s3 = s3 * __expf(m3 - mn) + os * __expf(om - mn); m3 = mn;
    }
    int sub = lane & 15;     // 16 float4-columns
    int slot = lane >> 4;    // 4 edge slots
    int h = sub >> 2;        // head of this lane's 4 channels
    float mh = (h == 0) ? m0 : (h == 1) ? m1 : (h == 2) ? m2 : m3;
    float sh = (h == 0) ? s0 : (h == 1) ? s1 : (h == 2) ? s2 : s3;
    float inv = 1.f / (sh + 1e-16f);
    float arh = (h == 0) ? ar0 : (h == 1) ? arv1 : (h == 2) ? arv2 : arv3;

    // ---- pass 2: 4 edges x 16 lanes x float4 gather-accumulate ----
    bool small = (deg <= 64);   // wave-uniform
    float ax = 0.f, ay = 0.f, az = 0.f, aw = 0.f;
    for (int base = rs; base < re; base += 4) {
        int es = base + slot;
        int idx = (es - rs) & 63;
        // all lanes active: shuffles well-defined
        int s_sh = __shfl(src_reg, idx, 64);
        float q0 = __shfl(l0, idx, 64);
        float q1 = __shfl(l1, idx, 64);
        float q2 = __shfl(l2, idx, 64);
        float q3 = __shfl(l3, idx, 64);
        if (es < re) {
            int s;
            float le;
            if (small) {
                s = s_sh;
                le = (h == 0) ? q0 : (h == 1) ? q1 : (h == 2) ? q2 : q3;
            } else {
                s = sorted_src[es];
                le = leaky(al1[s * 4 + h] + arh);
            }
            float alpha = __expf(le - mh) * inv;
            const float4 xv = *(const float4*)(xlin1 + (size_t)s * D1 + sub * 4);
            ax += xv.x * alpha; ay += xv.y * alpha;
            az += xv.z * alpha; aw += xv.w * alpha;
        }
    }
#pragma unroll
    for (int off = 16; off < 64; off <<= 1) {
        ax += __shfl_xor(ax, off, 64);
        ay += __shfl_xor(ay, off, 64);
        az += __shfl_xor(az, off, 64);
        aw += __shfl_xor(aw, off, 64);
    }
    if (slot == 0) {
        float4* p = (float4*)(acc1 + (size_t)d * D1 + sub * 4);
        float4 r = *p;
        r.x += ax; r.y += ay; r.z += az; r.w += aw;
        *p = r;
    }
}

// ================= ELU =================
__global__ void elu_kernel(float* __restrict__ a, int n) {
    int i = blockIdx.x * blockDim.x + threadIdx.x;
    if (i >= n) return;
    float v = a[i];
    a[i] = v > 0.f ? v : (__expf(v) - 1.f);
}

// ================= Layer 2 node phase =================
__global__ void node2_kernel(const float* __restrict__ h,
                             const float* __restrict__ W2,
                             const float* __restrict__ attl2,
                             const float* __restrict__ attr2,
                             const float* __restrict__ b2,
                             float* __restrict__ xlin2,
                             float* __restrict__ out,
                             float* __restrict__ al2,
                             float* __restrict__ ar2) {
    int node = blockIdx.x;
    int t = threadIdx.x;  // 0..63
    __shared__ float hs[D1];
    hs[t] = h[(size_t)node * D1 + t];
    __syncthreads();
    float acc = 0.f;
    for (int k = 0; k < D1; k++) acc += hs[k] * W2[k * OUT_DIM + t];
    xlin2[(size_t)node * OUT_DIM + t] = acc;
    out[(size_t)node * OUT_DIM + t] = acc + b2[t];  // residual (=x_lin) + bias
    float pl = acc * attl2[t];
    float pr = acc * attr2[t];
#pragma unroll
    for (int off = 32; off > 0; off >>= 1) {
        pl += __shfl_down(pl, off, 64);
        pr += __shfl_down(pr, off, 64);
    }
    if (t == 0) {
        al2[node] = pl;
        ar2[node] = pr;
    }
}

// ================= Fused aggregation, layer 2 (H=1, C=64) =================
__global__ __launch_bounds__(256) void agg2_kernel(
        const int* __restrict__ sorted_src, const int* __restrict__ row_ptr,
        const int* __restrict__ counts,
        const float* __restrict__ al2, const float* __restrict__ ar2,
        const float* __restrict__ xlin2, float* __restrict__ out) {
    int d = blockIdx.x * 4 + (threadIdx.x >> 6);
    if (d >= NN) return;
    int lane = threadIdx.x & 63;
    int rs = row_ptr[d];
    int deg = counts[d];
    int re = rs + deg;
    float ard = ar2[d];

    float m = -1e30f, s = 0.f;
    int src_reg = 0;
    float lreg = 0.f;
    for (int e = rs + lane; e < re; e += 64) {
        int sv = sorted_src[e];
        src_reg = sv;
        lreg = leaky(al2[sv] + ard);
        float mn = fmaxf(m, lreg);
        s = s * __expf(m - mn) + __expf(lreg - mn);
        m = mn;
    }
#pragma unroll
    for (int off = 1; off < 64; off <<= 1) {
        float om = __shfl_xor(m, off, 64);
        float os = __shfl_xor(s, off, 64);
        float mn = fmaxf(m, om);
        s = s * __expf(m - mn) + os * __expf(om - mn);
        m = mn;
    }
    float inv = 1.f / (s + 1e-16f);
    int sub = lane & 15;
    int slot = lane >> 4;

    bool small = (deg <= 64);
    float ax = 0.f, ay = 0.f, az = 0.f, aw = 0.f;
    for (int base = rs; base < re; base += 4) {
        int es = base + slot;
        int idx = (es - rs) & 63;
        int s_sh = __shfl(src_reg, idx, 64);
        float q = __shfl(lreg, idx, 64);
        if (es < re) {
            int sv;
            float le;
            if (small) { sv = s_sh; le = q; }
            else       { sv = sorted_src[es]; le = leaky(al2[sv] + ard); }
            float alpha = __expf(le - m) * inv;
            const float4 xv = *(const float4*)(xlin2 + (size_t)sv * OUT_DIM + sub * 4);
            ax += xv.x * alpha; ay += xv.y * alpha;
            az += xv.z * alpha; aw += xv.w * alpha;
        }
    }
#pragma unroll
    for (int off = 16; off < 64; off <<= 1) {
        ax += __shfl_xor(ax, off, 64);
        ay += __shfl_xor(ay, off, 64);
        az += __shfl_xor(az, off, 64);
        aw += __shfl_xor(aw, off, 64);
    }
    if (slot == 0) {
        float4* p = (float4*)(out + (size_t)d * OUT_DIM + sub * 4);
        float4 r = *p;
        r.x += ax; r.y += ay; r.z += az; r.w += aw;
        *p = r;
    }
}

extern "C" void kernel_launch(void* const* d_in, const int* in_sizes, int n_in,
                              void* d_out, int out_size, void* d_ws, size_t ws_size,
                              hipStream_t stream) {
    const float* x     = (const float*)d_in[0];
    const int*   eidx  = (const int*)d_in[1];
    const float* W1    = (const float*)d_in[2];
    const float* attl1 = (const float*)d_in[3];
    const float* attr1 = (const float*)d_in[4];
    const float* resW1 = (const float*)d_in[5];
    const float* b1    = (const float*)d_in[6];
    const float* W2    = (const float*)d_in[7];
    const float* attl2 = (const float*)d_in[8];
    const float* attr2 = (const float*)d_in[9];
    const float* b2    = (const float*)d_in[10];

    const int* src = eidx;
    const int* dst = eidx + EE;

    // workspace layout
    float* ws = (float*)d_ws;
    float* xlin1 = ws;                         // N*64 (reused as xlin2 later)
    float* acc1  = xlin1 + (size_t)NN * D1;    // N*64 (becomes h after elu)
    float* al1   = acc1 + (size_t)NN * D1;     // N*4
    float* ar1   = al1 + (size_t)NN * HEADS;   // N*4
    float* al2   = ar1 + (size_t)NN * HEADS;   // N
    float* ar2   = al2 + NN;                   // N
    int* counts     = (int*)(ar2 + NN);        // N
    int* row_ptr    = counts + NN;             // N
    int* cursor     = row_ptr + NN;            // N
    int* blocksums  = cursor + NN;             // 512
    int* sorted_src = blocksums + 512;         // E
    float* xlin2 = xlin1;                      // alias: xlin1 dead after agg1

    float* out = (float*)d_out;

    // CSR build (interleaved with node1, all on stream)
    zero_counts<<<(NN + 255) / 256, 256, 0, stream>>>(counts);
    node1_kernel<<<NN / NPB1, 128, 0, stream>>>(x, W1, resW1, attl1, attr1, b1,
                                                xlin1, acc1, al1, ar1);
    hist_kernel<<<(EE + 255) / 256, 256, 0, stream>>>(dst, counts);
    scan_local<<<SCAN_BLOCKS, 256, 0, stream>>>(counts, row_ptr, blocksums);
    scan_top<<<1, 512, 0, stream>>>(blocksums);
    scan_add<<<SCAN_BLOCKS, 256, 0, stream>>>(row_ptr, blocksums, cursor);
    scatter_kernel<<<(EE + 255) / 256, 256, 0, stream>>>(src, dst, cursor, sorted_src);

    // layer 1 aggregation (fused max+sum+msg, no atomics)
    agg1_kernel<<<(NN + 3) / 4, 256, 0, stream>>>(sorted_src, row_ptr, counts,
                                                  al1, ar1, xlin1, acc1);
    elu_kernel<<<(NN * D1 + 255) / 256, 256, 0, stream>>>(acc1, NN * D1);

    // layer 2
    node2_kernel<<<NN, 64, 0, stream>>>(acc1, W2, attl2, attr2, b2,
                                        xlin2, out, al2, ar2);
    agg2_kernel<<<(NN + 3) / 4, 256, 0, stream>>>(sorted_src, row_ptr, counts,
                                                  al2, ar2, xlin2, out);
}

// Round 3
// 428.455 us; speedup vs baseline: 3.9338x; 1.3805x over previous
//
#include <hip/hip_runtime.h>
#include <hip/hip_bf16.h>
#include <math.h>

// AGDN: 2-layer graph attention. N=100000, E=1600000, IN=128, HID=16, HEADS=4, OUT=64.
// CSR build via bucketed 2-pass sort (LDS-staged, coalesced/XCD-local writes),
// then fused gather-aggregate per layer (online softmax, no atomics on features).
#define NN 100000
#define EE 1600000
#define IN_DIM 128
#define HID 16
#define HEADS 4
#define D1 64            // HEADS*HID
#define OUT_DIM 64
#define SLOPE 0.2f

#define NB 391                 // ceil(N/256) buckets of 256 nodes
#define BINA_CHUNK 4096
#define BINA_BLOCKS ((EE + BINA_CHUNK - 1) / BINA_CHUNK)   // 391

__device__ __forceinline__ float leaky(float v) { return v > 0.f ? v : SLOPE * v; }

// ================= Layer 1 node phase =================
// 16 nodes per block, 128 threads. t<64: x_lin1 col t. t>=64: residual col t-64.
#define NPB1 16
__global__ void node1_kernel(const float* __restrict__ x,
                             const float* __restrict__ W1,
                             const float* __restrict__ resW,
                             const float* __restrict__ attl,
                             const float* __restrict__ attr,
                             const float* __restrict__ b1,
                             float* __restrict__ xlin1,
                             float* __restrict__ acc1,
                             float* __restrict__ al1,
                             float* __restrict__ ar1) {
    int base = blockIdx.x * NPB1;
    int t = threadIdx.x;  // 0..127
    __shared__ float xs[NPB1][IN_DIM];   // 8KB
    __shared__ float xl[NPB1][D1];       // 4KB

    for (int i = t; i < NPB1 * IN_DIM; i += 128) {
        int n = i >> 7, k = i & 127;
        xs[n][k] = x[(size_t)(base + n) * IN_DIM + k];
    }
    __syncthreads();

    int col = t & 63;
    const float* Wp = (t < 64) ? W1 : resW;
    float acc[NPB1];
#pragma unroll
    for (int n = 0; n < NPB1; n++) acc[n] = 0.f;
    for (int k = 0; k < IN_DIM; k++) {
        float w = Wp[k * D1 + col];
#pragma unroll
        for (int n = 0; n < NPB1; n++) acc[n] += xs[n][k] * w;
    }
    if (t < 64) {
#pragma unroll
        for (int n = 0; n < NPB1; n++) {
            xlin1[(size_t)(base + n) * D1 + col] = acc[n];
            xl[n][col] = acc[n];
        }
    } else {
        float bv = b1[col];
#pragma unroll
        for (int n = 0; n < NPB1; n++) {
            acc1[(size_t)(base + n) * D1 + col] = acc[n] + bv;
        }
    }
    __syncthreads();
    // attention dots: 128 threads -> 16 nodes x (4 heads left + 4 heads right)
    {
        int n = t >> 3;
        int q = t & 7;
        int h = q & 3;
        const float* att = (q < 4) ? attl : attr;
        float s = 0.f;
#pragma unroll
        for (int c = 0; c < HID; c++) s += xl[n][h * HID + c] * att[h * HID + c];
        if (q < 4) al1[(base + n) * HEADS + h] = s;
        else       ar1[(base + n) * HEADS + h] = s;
    }
}

// ================= CSR build: bucketed two-pass sort =================
__global__ void zero_buckets(int* __restrict__ bucket_counts) {
    int t = threadIdx.x;
    if (t < NB) bucket_counts[t] = 0;
}

__global__ __launch_bounds__(256) void coarse_hist(const int* __restrict__ dst,
                                                   int* __restrict__ bucket_counts) {
    __shared__ int lh[512];
    int t = threadIdx.x;
    lh[t] = 0; lh[t + 256] = 0;
    __syncthreads();
    int e0 = blockIdx.x * BINA_CHUNK;
#pragma unroll
    for (int i = 0; i < 16; i++) {
        int e = e0 + t + i * 256;
        if (e < EE) atomicAdd(&lh[dst[e] >> 8], 1);
    }
    __syncthreads();
    for (int j = t; j < NB; j += 256) {
        int c = lh[j];
        if (c) atomicAdd(&bucket_counts[j], c);
    }
}

__global__ void coarse_scan(const int* __restrict__ bucket_counts,
                            int* __restrict__ bucket_ptr,
                            int* __restrict__ bucket_cursor) {
    __shared__ int tmp[512];
    int t = threadIdx.x;  // 512 threads
    int v = (t < NB) ? bucket_counts[t] : 0;
    tmp[t] = v;
    __syncthreads();
    for (int off = 1; off < 512; off <<= 1) {
        int a = (t >= off) ? tmp[t - off] : 0;
        __syncthreads();
        tmp[t] += a;
        __syncthreads();
    }
    if (t < NB) {
        int ex = tmp[t] - v;
        bucket_ptr[t] = ex;
        bucket_cursor[t] = ex;
    }
}

// multi-split: chunk of 4096 edges -> bucket-grouped coalesced writes of packed edges
__global__ __launch_bounds__(256) void binA_kernel(const int* __restrict__ src,
                                                   const int* __restrict__ dst,
                                                   int* __restrict__ bucket_cursor,
                                                   unsigned* __restrict__ binned) {
    __shared__ unsigned spack[BINA_CHUNK];       // 16KB
    __shared__ unsigned short sbkt[BINA_CHUNK];  // 8KB
    __shared__ int lhist[512], lscan[512], gbase[512], lcur[512];  // 8KB
    int t = threadIdx.x;
    lhist[t] = 0; lhist[t + 256] = 0;
    lcur[t] = 0;  lcur[t + 256] = 0;
    __syncthreads();
    int e0 = blockIdx.x * BINA_CHUNK;
    int nvalid = EE - e0; if (nvalid > BINA_CHUNK) nvalid = BINA_CHUNK;
    unsigned pk[16];
    unsigned short bk[16];
#pragma unroll
    for (int i = 0; i < 16; i++) {
        int e = e0 + t + i * 256;
        if (e < EE) {
            int d = dst[e], s = src[e];
            int b = d >> 8;
            pk[i] = ((unsigned)(d & 255) << 24) | (unsigned)s;
            bk[i] = (unsigned short)b;
            atomicAdd(&lhist[b], 1);
        } else bk[i] = 0xFFFFu;
    }
    __syncthreads();
    int c1 = lhist[t], c2 = lhist[t + 256];
    // inclusive Hillis-Steele scan over 512
    for (int off = 1; off < 512; off <<= 1) {
        int a1 = (t >= off) ? lhist[t - off] : 0;
        int a2 = (t + 256 >= off) ? lhist[t + 256 - off] : 0;
        __syncthreads();
        lhist[t] += a1; lhist[t + 256] += a2;
        __syncthreads();
    }
    lscan[t] = lhist[t] - c1;
    lscan[t + 256] = lhist[t + 256] - c2;
    if (c1) gbase[t] = atomicAdd(&bucket_cursor[t], c1);
    if (c2) gbase[t + 256] = atomicAdd(&bucket_cursor[t + 256], c2);
    __syncthreads();
#pragma unroll
    for (int i = 0; i < 16; i++) {
        if (bk[i] != 0xFFFFu) {
            int b = bk[i];
            int pos = atomicAdd(&lcur[b], 1);
            int slot = lscan[b] + pos;
            spack[slot] = pk[i];
            sbkt[slot] = (unsigned short)b;
        }
    }
    __syncthreads();
    for (int j = t; j < nvalid; j += 256) {
        int b = sbkt[j];
        binned[gbase[b] + (j - lscan[b])] = spack[j];
    }
}

// per-bucket exact counting sort; also emits row_ptr and counts (no global hist/scan needed)
__global__ __launch_bounds__(256) void binB_kernel(const unsigned* __restrict__ binned,
                                                   const int* __restrict__ bucket_ptr,
                                                   const int* __restrict__ bucket_counts,
                                                   int* __restrict__ row_ptr,
                                                   int* __restrict__ counts,
                                                   int* __restrict__ sorted_src) {
    __shared__ int lcount[256], lrow[256], lcur[256];
    int b = blockIdx.x, t = threadIdx.x;
    int start = bucket_ptr[b];
    int cnt = bucket_counts[b];
    lcount[t] = 0;
    __syncthreads();
    for (int i = t; i < cnt; i += 256) {
        atomicAdd(&lcount[binned[start + i] >> 24], 1);
    }
    __syncthreads();
    int v = lcount[t];
    lrow[t] = v;
    __syncthreads();
    for (int off = 1; off < 256; off <<= 1) {
        int a = (t >= off) ? lrow[t - off] : 0;
        __syncthreads();
        lrow[t] += a;
        __syncthreads();
    }
    int ex = lrow[t] - v;   // exclusive
    __syncthreads();
    lrow[t] = ex;
    lcur[t] = 0;
    int node = (b << 8) + t;
    if (node < NN) {
        row_ptr[node] = start + ex;
        counts[node] = v;
    }
    __syncthreads();
    for (int i = t; i < cnt; i += 256) {
        unsigned p = binned[start + i];
        int low = p >> 24;
        int pos = atomicAdd(&lcur[low], 1);
        sorted_src[start + lrow[low] + pos] = (int)(p & 0xFFFFFFu);
    }
}

// ================= Fused aggregation, layer 1 (H=4, C=16) + ELU =================
__global__ __launch_bounds__(256) void agg1_kernel(
        const int* __restrict__ sorted_src, const int* __restrict__ row_ptr,
        const int* __restrict__ counts,
        const float* __restrict__ al1, const float* __restrict__ ar1,
        const float* __restrict__ xlin1, float* __restrict__ acc1) {
    int d = blockIdx.x * 4 + (threadIdx.x >> 6);
    if (d >= NN) return;
    int lane = threadIdx.x & 63;
    int rs = row_ptr[d];
    int deg = counts[d];
    int re = rs + deg;
    float ar0 = ar1[d * 4 + 0], arv1 = ar1[d * 4 + 1];
    float arv2 = ar1[d * 4 + 2], arv3 = ar1[d * 4 + 3];

    // ---- pass 1: edge-parallel online softmax ----
    float m0 = -1e30f, m1 = -1e30f, m2 = -1e30f, m3 = -1e30f;
    float s0 = 0.f, s1 = 0.f, s2 = 0.f, s3 = 0.f;
    int src_reg = 0;
    float l0 = 0.f, l1 = 0.f, l2 = 0.f, l3 = 0.f;
    for (int e = rs + lane; e < re; e += 64) {
        int s = sorted_src[e];
        src_reg = s;
        l0 = leaky(al1[s * 4 + 0] + ar0);
        l1 = leaky(al1[s * 4 + 1] + arv1);
        l2 = leaky(al1[s * 4 + 2] + arv2);
        l3 = leaky(al1[s * 4 + 3] + arv3);
        float mn;
        mn = fmaxf(m0, l0); s0 = s0 * __expf(m0 - mn) + __expf(l0 - mn); m0 = mn;
        mn = fmaxf(m1, l1); s1 = s1 * __expf(m1 - mn) + __expf(l1 - mn); m1 = mn;
        mn = fmaxf(m2, l2); s2 = s2 * __expf(m2 - mn) + __expf(l2 - mn); m2 = mn;
        mn = fmaxf(m3, l3); s3 = s3 * __expf(m3 - mn) + __expf(l3 - mn); m3 = mn;
    }
#pragma unroll
    for (int off = 1; off < 64; off <<= 1) {
        float om, os, mn;
        om = __shfl_xor(m0, off, 64); os = __shfl_xor(s0, off, 64);
        mn = fmaxf(m0, om); s0 = s0 * __expf(m0 - mn) + os * __expf(om - mn); m0 = mn;
        om = __shfl_xor(m1, off, 64); os = __shfl_xor(s1, off, 64);
        mn = fmaxf(m1, om); s1 = s1 * __expf(m1 - mn) + os * __expf(om - mn); m1 = mn;
        om = __shfl_xor(m2, off, 64); os = __shfl_xor(s2, off, 64);
        mn = fmaxf(m2, om); s2 = s2 * __expf(m2 - mn) + os * __expf(om - mn); m2 = mn;
        om = __shfl_xor(m3, off, 64); os = __shfl_xor(s3, off, 64);
        mn = fmaxf(m3, om); s3 = s3 * __expf(m3 - mn) + os * __expf(om - mn); m3 = mn;
    }
    int sub = lane & 15;     // 16 float4-columns
    int slot = lane >> 4;    // 4 edge slots
    int h = sub >> 2;        // head of this lane's 4 channels
    float mh = (h == 0) ? m0 : (h == 1) ? m1 : (h == 2) ? m2 : m3;
    float sh = (h == 0) ? s0 : (h == 1) ? s1 : (h == 2) ? s2 : s3;
    float inv = 1.f / (sh + 1e-16f);
    float arh = (h == 0) ? ar0 : (h == 1) ? arv1 : (h == 2) ? arv2 : arv3;

    // ---- pass 2: 4 edges x 16 lanes x float4 gather-accumulate ----
    bool small = (deg <= 64);   // wave-uniform
    float ax = 0.f, ay = 0.f, az = 0.f, aw = 0.f;
    for (int base = rs; base < re; base += 4) {
        int es = base + slot;
        int idx = (es - rs) & 63;
        int s_sh = __shfl(src_reg, idx, 64);
        float q0 = __shfl(l0, idx, 64);
        float q1 = __shfl(l1, idx, 64);
        float q2 = __shfl(l2, idx, 64);
        float q3 = __shfl(l3, idx, 64);
        if (es < re) {
            int s;
            float le;
            if (small) {
                s = s_sh;
                le = (h == 0) ? q0 : (h == 1) ? q1 : (h == 2) ? q2 : q3;
            } else {
                s = sorted_src[es];
                le = leaky(al1[s * 4 + h] + arh);
            }
            float alpha = __expf(le - mh) * inv;
            const float4 xv = *(const float4*)(xlin1 + (size_t)s * D1 + sub * 4);
            ax += xv.x * alpha; ay += xv.y * alpha;
            az += xv.z * alpha; aw += xv.w * alpha;
        }
    }
#pragma unroll
    for (int off = 16; off < 64; off <<= 1) {
        ax += __shfl_xor(ax, off, 64);
        ay += __shfl_xor(ay, off, 64);
        az += __shfl_xor(az, off, 64);
        aw += __shfl_xor(aw, off, 64);
    }
    if (slot == 0) {
        float4* p = (float4*)(acc1 + (size_t)d * D1 + sub * 4);
        float4 r = *p;
        r.x += ax; r.y += ay; r.z += az; r.w += aw;
        // fused ELU
        r.x = r.x > 0.f ? r.x : (__expf(r.x) - 1.f);
        r.y = r.y > 0.f ? r.y : (__expf(r.y) - 1.f);
        r.z = r.z > 0.f ? r.z : (__expf(r.z) - 1.f);
        r.w = r.w > 0.f ? r.w : (__expf(r.w) - 1.f);
        *p = r;
    }
}

// ================= Layer 2 node phase =================
// 64 nodes per 256-thread block (4 waves x 16 nodes); W2 stays L1-resident.
#define NPB2 64
__global__ __launch_bounds__(256) void node2_kernel(const float* __restrict__ h,
                             const float* __restrict__ W2,
                             const float* __restrict__ attl2,
                             const float* __restrict__ attr2,
                             const float* __restrict__ b2,
                             float* __restrict__ xlin2,
                             float* __restrict__ out,
                             float* __restrict__ al2,
                             float* __restrict__ ar2) {
    int base = blockIdx.x * NPB2;
    int t = threadIdx.x;
    __shared__ float hs[NPB2][D1];   // 16KB
    for (int i = t; i < NPB2 * D1; i += 256) {
        int n = i >> 6, k = i & 63;
        int node = base + n;
        hs[n][k] = (node < NN) ? h[(size_t)node * D1 + k] : 0.f;
    }
    __syncthreads();
    int wave = t >> 6, lane = t & 63;
    int nb = wave * 16;
    float acc[16];
#pragma unroll
    for (int n = 0; n < 16; n++) acc[n] = 0.f;
    for (int k = 0; k < D1; k += 4) {
        float w0 = W2[(k + 0) * OUT_DIM + lane];
        float w1 = W2[(k + 1) * OUT_DIM + lane];
        float w2 = W2[(k + 2) * OUT_DIM + lane];
        float w3 = W2[(k + 3) * OUT_DIM + lane];
#pragma unroll
        for (int n = 0; n < 16; n++) {
            const float4 h4 = *(const float4*)&hs[nb + n][k];
            acc[n] += h4.x * w0 + h4.y * w1 + h4.z * w2 + h4.w * w3;
        }
    }
    float bl = attl2[lane], br = attr2[lane], bv = b2[lane];
#pragma unroll
    for (int n = 0; n < 16; n++) {
        int node = base + nb + n;
        if (node < NN) {
            xlin2[(size_t)node * OUT_DIM + lane] = acc[n];
            out[(size_t)node * OUT_DIM + lane] = acc[n] + bv;
        }
        float pl = acc[n] * bl, pr = acc[n] * br;
#pragma unroll
        for (int off = 32; off > 0; off >>= 1) {
            pl += __shfl_down(pl, off, 64);
            pr += __shfl_down(pr, off, 64);
        }
        if (lane == 0 && node < NN) { al2[node] = pl; ar2[node] = pr; }
    }
}

// ================= Fused aggregation, layer 2 (H=1, C=64) =================
__global__ __launch_bounds__(256) void agg2_kernel(
        const int* __restrict__ sorted_src, const int* __restrict__ row_ptr,
        const int* __restrict__ counts,
        const float* __restrict__ al2, const float* __restrict__ ar2,
        const float* __restrict__ xlin2, float* __restrict__ out) {
    int d = blockIdx.x * 4 + (threadIdx.x >> 6);
    if (d >= NN) return;
    int lane = threadIdx.x & 63;
    int rs = row_ptr[d];
    int deg = counts[d];
    int re = rs + deg;
    float ard = ar2[d];

    float m = -1e30f, s = 0.f;
    int src_reg = 0;
    float lreg = 0.f;
    for (int e = rs + lane; e < re; e += 64) {
        int sv = sorted_src[e];
        src_reg = sv;
        lreg = leaky(al2[sv] + ard);
        float mn = fmaxf(m, lreg);
        s = s * __expf(m - mn) + __expf(lreg - mn);
        m = mn;
    }
#pragma unroll
    for (int off = 1; off < 64; off <<= 1) {
        float om = __shfl_xor(m, off, 64);
        float os = __shfl_xor(s, off, 64);
        float mn = fmaxf(m, om);
        s = s * __expf(m - mn) + os * __expf(om - mn);
        m = mn;
    }
    float inv = 1.f / (s + 1e-16f);
    int sub = lane & 15;
    int slot = lane >> 4;

    bool small = (deg <= 64);
    float ax = 0.f, ay = 0.f, az = 0.f, aw = 0.f;
    for (int base = rs; base < re; base += 4) {
        int es = base + slot;
        int idx = (es - rs) & 63;
        int s_sh = __shfl(src_reg, idx, 64);
        float q = __shfl(lreg, idx, 64);
        if (es < re) {
            int sv;
            float le;
            if (small) { sv = s_sh; le = q; }
            else       { sv = sorted_src[es]; le = leaky(al2[sv] + ard); }
            float alpha = __expf(le - m) * inv;
            const float4 xv = *(const float4*)(xlin2 + (size_t)sv * OUT_DIM + sub * 4);
            ax += xv.x * alpha; ay += xv.y * alpha;
            az += xv.z * alpha; aw += xv.w * alpha;
        }
    }
#pragma unroll
    for (int off = 16; off < 64; off <<= 1) {
        ax += __shfl_xor(ax, off, 64);
        ay += __shfl_xor(ay, off, 64);
        az += __shfl_xor(az, off, 64);
        aw += __shfl_xor(aw, off, 64);
    }
    if (slot == 0) {
        float4* p = (float4*)(out + (size_t)d * OUT_DIM + sub * 4);
        float4 r = *p;
        r.x += ax; r.y += ay; r.z += az; r.w += aw;
        *p = r;
    }
}

extern "C" void kernel_launch(void* const* d_in, const int* in_sizes, int n_in,
                              void* d_out, int out_size, void* d_ws, size_t ws_size,
                              hipStream_t stream) {
    const float* x     = (const float*)d_in[0];
    const int*   eidx  = (const int*)d_in[1];
    const float* W1    = (const float*)d_in[2];
    const float* attl1 = (const float*)d_in[3];
    const float* attr1 = (const float*)d_in[4];
    const float* resW1 = (const float*)d_in[5];
    const float* b1    = (const float*)d_in[6];
    const float* W2    = (const float*)d_in[7];
    const float* attl2 = (const float*)d_in[8];
    const float* attr2 = (const float*)d_in[9];
    const float* b2    = (const float*)d_in[10];

    const int* src = eidx;
    const int* dst = eidx + EE;

    // workspace layout
    float* ws = (float*)d_ws;
    float* xlin1 = ws;                         // N*64 (reused as xlin2)
    float* acc1  = xlin1 + (size_t)NN * D1;    // N*64 (residual+bias -> h)
    float* al1   = acc1 + (size_t)NN * D1;     // N*4
    float* ar1   = al1 + (size_t)NN * HEADS;   // N*4
    float* al2   = ar1 + (size_t)NN * HEADS;   // N
    float* ar2   = al2 + NN;                   // N
    int* counts        = (int*)(ar2 + NN);     // N
    int* row_ptr       = counts + NN;          // N
    int* bucket_counts = row_ptr + NN;         // 512
    int* bucket_ptr    = bucket_counts + 512;  // 512
    int* bucket_cursor = bucket_ptr + 512;     // 512
    int* sorted_src    = bucket_cursor + 512;  // E
    unsigned* binned = (unsigned*)acc1;        // alias: E u32, dead before node1 runs
    float* xlin2 = xlin1;                      // alias: xlin1 dead after agg1

    float* out = (float*)d_out;

    // ---- CSR build (bucketed 2-pass sort) ----
    zero_buckets<<<1, 512, 0, stream>>>(bucket_counts);
    coarse_hist<<<BINA_BLOCKS, 256, 0, stream>>>(dst, bucket_counts);
    coarse_scan<<<1, 512, 0, stream>>>(bucket_counts, bucket_ptr, bucket_cursor);
    binA_kernel<<<BINA_BLOCKS, 256, 0, stream>>>(src, dst, bucket_cursor, binned);
    binB_kernel<<<NB, 256, 0, stream>>>(binned, bucket_ptr, bucket_counts,
                                        row_ptr, counts, sorted_src);

    // ---- layer 1 ----
    node1_kernel<<<NN / NPB1, 128, 0, stream>>>(x, W1, resW1, attl1, attr1, b1,
                                                xlin1, acc1, al1, ar1);
    agg1_kernel<<<(NN + 3) / 4, 256, 0, stream>>>(sorted_src, row_ptr, counts,
                                                  al1, ar1, xlin1, acc1);

    // ---- layer 2 ----
    node2_kernel<<<(NN + NPB2 - 1) / NPB2, 256, 0, stream>>>(acc1, W2, attl2, attr2, b2,
                                                             xlin2, out, al2, ar2);
    agg2_kernel<<<(NN + 3) / 4, 256, 0, stream>>>(sorted_src, row_ptr, counts,
                                                  al2, ar2, xlin2, out);
}

// Round 4
// 400.554 us; speedup vs baseline: 4.2078x; 1.0697x over previous
//
#include <hip/hip_runtime.h>
#include <hip/hip_bf16.h>
#include <math.h>

// AGDN: 2-layer graph attention. N=100000, E=1600000, IN=128, HID=16, HEADS=4, OUT=64.
// CSR build via bucketed 2-pass sort; fused gather-aggregate per layer with
// two-phase exact softmax (alphas precomputed to per-wave LDS) and bf16 xlin
// for the random gather (halves fetch).
#define NN 100000
#define EE 1600000
#define IN_DIM 128
#define HID 16
#define HEADS 4
#define D1 64            // HEADS*HID
#define OUT_DIM 64
#define SLOPE 0.2f

#define NB 391                 // ceil(N/256) buckets of 256 nodes
#define BINA_CHUNK 4096
#define BINA_BLOCKS ((EE + BINA_CHUNK - 1) / BINA_CHUNK)   // 391

__device__ __forceinline__ float leaky(float v) { return v > 0.f ? v : SLOPE * v; }
__device__ __forceinline__ float bflo(unsigned u) { return __uint_as_float(u << 16); }
__device__ __forceinline__ float bfhi(unsigned u) { return __uint_as_float(u & 0xFFFF0000u); }

// ================= Layer 1 node phase =================
// 16 nodes per block, 128 threads. t<64: x_lin1 col t (bf16 out). t>=64: residual col t-64.
#define NPB1 16
__global__ void node1_kernel(const float* __restrict__ x,
                             const float* __restrict__ W1,
                             const float* __restrict__ resW,
                             const float* __restrict__ attl,
                             const float* __restrict__ attr,
                             const float* __restrict__ b1,
                             __hip_bfloat16* __restrict__ xlin1b,
                             float* __restrict__ acc1,
                             float* __restrict__ al1,
                             float* __restrict__ ar1) {
    int base = blockIdx.x * NPB1;
    int t = threadIdx.x;  // 0..127
    __shared__ float xs[NPB1][IN_DIM];   // 8KB
    __shared__ float xl[NPB1][D1];       // 4KB

    for (int i = t; i < NPB1 * IN_DIM; i += 128) {
        int n = i >> 7, k = i & 127;
        xs[n][k] = x[(size_t)(base + n) * IN_DIM + k];
    }
    __syncthreads();

    int col = t & 63;
    const float* Wp = (t < 64) ? W1 : resW;
    float acc[NPB1];
#pragma unroll
    for (int n = 0; n < NPB1; n++) acc[n] = 0.f;
    for (int k = 0; k < IN_DIM; k++) {
        float w = Wp[k * D1 + col];
#pragma unroll
        for (int n = 0; n < NPB1; n++) acc[n] += xs[n][k] * w;
    }
    if (t < 64) {
#pragma unroll
        for (int n = 0; n < NPB1; n++) {
            xlin1b[(size_t)(base + n) * D1 + col] = __float2bfloat16(acc[n]);
            xl[n][col] = acc[n];
        }
    } else {
        float bv = b1[col];
#pragma unroll
        for (int n = 0; n < NPB1; n++) {
            acc1[(size_t)(base + n) * D1 + col] = acc[n] + bv;
        }
    }
    __syncthreads();
    // attention dots: 128 threads -> 16 nodes x (4 heads left + 4 heads right)
    {
        int n = t >> 3;
        int q = t & 7;
        int h = q & 3;
        const float* att = (q < 4) ? attl : attr;
        float s = 0.f;
#pragma unroll
        for (int c = 0; c < HID; c++) s += xl[n][h * HID + c] * att[h * HID + c];
        if (q < 4) al1[(base + n) * HEADS + h] = s;
        else       ar1[(base + n) * HEADS + h] = s;
    }
}

// ================= CSR build: bucketed two-pass sort =================
__global__ void zero_buckets(int* __restrict__ bucket_counts) {
    int t = threadIdx.x;
    if (t < NB) bucket_counts[t] = 0;
}

__global__ __launch_bounds__(256) void coarse_hist(const int* __restrict__ dst,
                                                   int* __restrict__ bucket_counts) {
    __shared__ int lh[512];
    int t = threadIdx.x;
    lh[t] = 0; lh[t + 256] = 0;
    __syncthreads();
    int e0 = blockIdx.x * BINA_CHUNK;
#pragma unroll
    for (int i = 0; i < 16; i++) {
        int e = e0 + t + i * 256;
        if (e < EE) atomicAdd(&lh[dst[e] >> 8], 1);
    }
    __syncthreads();
    for (int j = t; j < NB; j += 256) {
        int c = lh[j];
        if (c) atomicAdd(&bucket_counts[j], c);
    }
}

__global__ void coarse_scan(const int* __restrict__ bucket_counts,
                            int* __restrict__ bucket_ptr,
                            int* __restrict__ bucket_cursor) {
    __shared__ int tmp[512];
    int t = threadIdx.x;  // 512 threads
    int v = (t < NB) ? bucket_counts[t] : 0;
    tmp[t] = v;
    __syncthreads();
    for (int off = 1; off < 512; off <<= 1) {
        int a = (t >= off) ? tmp[t - off] : 0;
        __syncthreads();
        tmp[t] += a;
        __syncthreads();
    }
    if (t < NB) {
        int ex = tmp[t] - v;
        bucket_ptr[t] = ex;
        bucket_cursor[t] = ex;
    }
}

// multi-split: chunk of 4096 edges -> bucket-grouped coalesced writes of packed edges
__global__ __launch_bounds__(256) void binA_kernel(const int* __restrict__ src,
                                                   const int* __restrict__ dst,
                                                   int* __restrict__ bucket_cursor,
                                                   unsigned* __restrict__ binned) {
    __shared__ unsigned spack[BINA_CHUNK];       // 16KB
    __shared__ unsigned short sbkt[BINA_CHUNK];  // 8KB
    __shared__ int lhist[512], lscan[512], gbase[512], lcur[512];  // 8KB
    int t = threadIdx.x;
    lhist[t] = 0; lhist[t + 256] = 0;
    lcur[t] = 0;  lcur[t + 256] = 0;
    __syncthreads();
    int e0 = blockIdx.x * BINA_CHUNK;
    int nvalid = EE - e0; if (nvalid > BINA_CHUNK) nvalid = BINA_CHUNK;
    unsigned pk[16];
    unsigned short bk[16];
#pragma unroll
    for (int i = 0; i < 16; i++) {
        int e = e0 + t + i * 256;
        if (e < EE) {
            int d = dst[e], s = src[e];
            int b = d >> 8;
            pk[i] = ((unsigned)(d & 255) << 24) | (unsigned)s;
            bk[i] = (unsigned short)b;
            atomicAdd(&lhist[b], 1);
        } else bk[i] = 0xFFFFu;
    }
    __syncthreads();
    int c1 = lhist[t], c2 = lhist[t + 256];
    for (int off = 1; off < 512; off <<= 1) {
        int a1 = (t >= off) ? lhist[t - off] : 0;
        int a2 = (t + 256 >= off) ? lhist[t + 256 - off] : 0;
        __syncthreads();
        lhist[t] += a1; lhist[t + 256] += a2;
        __syncthreads();
    }
    lscan[t] = lhist[t] - c1;
    lscan[t + 256] = lhist[t + 256] - c2;
    if (c1) gbase[t] = atomicAdd(&bucket_cursor[t], c1);
    if (c2) gbase[t + 256] = atomicAdd(&bucket_cursor[t + 256], c2);
    __syncthreads();
#pragma unroll
    for (int i = 0; i < 16; i++) {
        if (bk[i] != 0xFFFFu) {
            int b = bk[i];
            int pos = atomicAdd(&lcur[b], 1);
            int slot = lscan[b] + pos;
            spack[slot] = pk[i];
            sbkt[slot] = (unsigned short)b;
        }
    }
    __syncthreads();
    for (int j = t; j < nvalid; j += 256) {
        int b = sbkt[j];
        binned[gbase[b] + (j - lscan[b])] = spack[j];
    }
}

// per-bucket exact counting sort; also emits row_ptr and counts
__global__ __launch_bounds__(256) void binB_kernel(const unsigned* __restrict__ binned,
                                                   const int* __restrict__ bucket_ptr,
                                                   const int* __restrict__ bucket_counts,
                                                   int* __restrict__ row_ptr,
                                                   int* __restrict__ counts,
                                                   int* __restrict__ sorted_src) {
    __shared__ int lcount[256], lrow[256], lcur[256];
    int b = blockIdx.x, t = threadIdx.x;
    int start = bucket_ptr[b];
    int cnt = bucket_counts[b];
    lcount[t] = 0;
    __syncthreads();
    for (int i = t; i < cnt; i += 256) {
        atomicAdd(&lcount[binned[start + i] >> 24], 1);
    }
    __syncthreads();
    int v = lcount[t];
    lrow[t] = v;
    __syncthreads();
    for (int off = 1; off < 256; off <<= 1) {
        int a = (t >= off) ? lrow[t - off] : 0;
        __syncthreads();
        lrow[t] += a;
        __syncthreads();
    }
    int ex = lrow[t] - v;   // exclusive
    __syncthreads();
    lrow[t] = ex;
    lcur[t] = 0;
    int node = (b << 8) + t;
    if (node < NN) {
        row_ptr[node] = start + ex;
        counts[node] = v;
    }
    __syncthreads();
    for (int i = t; i < cnt; i += 256) {
        unsigned p = binned[start + i];
        int low = p >> 24;
        int pos = atomicAdd(&lcur[low], 1);
        sorted_src[start + lrow[low] + pos] = (int)(p & 0xFFFFFFu);
    }
}

// ================= Fused aggregation, layer 1 (H=4, C=16) + ELU =================
// One wave per dst node; 4 waves/block. Two-phase softmax, alpha via per-wave LDS,
// bf16 gather: 8 edge-slots x 8 sub-lanes x 8 channels.
__global__ __launch_bounds__(256) void agg1_kernel(
        const int* __restrict__ sorted_src, const int* __restrict__ row_ptr,
        const int* __restrict__ counts,
        const float* __restrict__ al1, const float* __restrict__ ar1,
        const __hip_bfloat16* __restrict__ xlin1b, float* __restrict__ acc1) {
    __shared__ int   s_srcs[4][64];
    __shared__ float s_alpha[4][64][4];
    int w = threadIdx.x >> 6;
    int d = blockIdx.x * 4 + w;
    if (d >= NN) return;
    int lane = threadIdx.x & 63;
    int rs = row_ptr[d];
    int deg = counts[d];
    int re = rs + deg;
    const float4 arv = *(const float4*)(ar1 + d * 4);  // wave-uniform
    int slot = lane >> 3;   // 8 edge slots
    int sub  = lane & 7;    // 8 channel groups of 8
    int h    = sub >> 1;    // head of this lane's 8 channels
    float acc[8];
#pragma unroll
    for (int j = 0; j < 8; j++) acc[j] = 0.f;
    const unsigned short* xb = (const unsigned short*)xlin1b;

    if (deg <= 64) {
        // ---- pass 1: one edge per lane, exact two-phase softmax ----
        int e = rs + lane;
        bool act = e < re;
        float l0 = -1e30f, l1 = -1e30f, l2 = -1e30f, l3 = -1e30f;
        int s = 0;
        if (act) {
            s = sorted_src[e];
            const float4 alv = *(const float4*)(al1 + s * 4);
            l0 = leaky(alv.x + arv.x); l1 = leaky(alv.y + arv.y);
            l2 = leaky(alv.z + arv.z); l3 = leaky(alv.w + arv.w);
        }
        float m0 = l0, m1 = l1, m2 = l2, m3 = l3;
#pragma unroll
        for (int off = 1; off < 64; off <<= 1) {
            m0 = fmaxf(m0, __shfl_xor(m0, off, 64));
            m1 = fmaxf(m1, __shfl_xor(m1, off, 64));
            m2 = fmaxf(m2, __shfl_xor(m2, off, 64));
            m3 = fmaxf(m3, __shfl_xor(m3, off, 64));
        }
        float e0 = act ? __expf(l0 - m0) : 0.f;
        float e1 = act ? __expf(l1 - m1) : 0.f;
        float e2 = act ? __expf(l2 - m2) : 0.f;
        float e3 = act ? __expf(l3 - m3) : 0.f;
        float s0 = e0, s1 = e1, s2 = e2, s3 = e3;
#pragma unroll
        for (int off = 1; off < 64; off <<= 1) {
            s0 += __shfl_xor(s0, off, 64);
            s1 += __shfl_xor(s1, off, 64);
            s2 += __shfl_xor(s2, off, 64);
            s3 += __shfl_xor(s3, off, 64);
        }
        if (act) {
            float4 alpha;
            alpha.x = e0 / (s0 + 1e-16f);
            alpha.y = e1 / (s1 + 1e-16f);
            alpha.z = e2 / (s2 + 1e-16f);
            alpha.w = e3 / (s3 + 1e-16f);
            s_srcs[w][lane] = s;
            *(float4*)&s_alpha[w][lane][0] = alpha;
        }
        // per-wave LDS, in-order within wave: no barrier needed
        // ---- pass 2: 8 edges x 8 lanes x 8 bf16 channels ----
        for (int b2 = rs; b2 < re; b2 += 8) {
            int es = b2 + slot;
            if (es < re) {
                int idx = es - rs;
                int sv = s_srcs[w][idx];
                float a = s_alpha[w][idx][h];
                const uint4 p = *(const uint4*)(xb + (size_t)sv * D1 + sub * 8);
                acc[0] += bflo(p.x) * a; acc[1] += bfhi(p.x) * a;
                acc[2] += bflo(p.y) * a; acc[3] += bfhi(p.y) * a;
                acc[4] += bflo(p.z) * a; acc[5] += bfhi(p.z) * a;
                acc[6] += bflo(p.w) * a; acc[7] += bfhi(p.w) * a;
            }
        }
    } else {
        // ---- fallback deg > 64: two-phase with recompute ----
        float m0 = -1e30f, m1 = -1e30f, m2 = -1e30f, m3 = -1e30f;
        for (int e = rs + lane; e < re; e += 64) {
            int s = sorted_src[e];
            const float4 alv = *(const float4*)(al1 + s * 4);
            m0 = fmaxf(m0, leaky(alv.x + arv.x));
            m1 = fmaxf(m1, leaky(alv.y + arv.y));
            m2 = fmaxf(m2, leaky(alv.z + arv.z));
            m3 = fmaxf(m3, leaky(alv.w + arv.w));
        }
#pragma unroll
        for (int off = 1; off < 64; off <<= 1) {
            m0 = fmaxf(m0, __shfl_xor(m0, off, 64));
            m1 = fmaxf(m1, __shfl_xor(m1, off, 64));
            m2 = fmaxf(m2, __shfl_xor(m2, off, 64));
            m3 = fmaxf(m3, __shfl_xor(m3, off, 64));
        }
        float s0 = 0.f, s1 = 0.f, s2 = 0.f, s3 = 0.f;
        for (int e = rs + lane; e < re; e += 64) {
            int s = sorted_src[e];
            const float4 alv = *(const float4*)(al1 + s * 4);
            s0 += __expf(leaky(alv.x + arv.x) - m0);
            s1 += __expf(leaky(alv.y + arv.y) - m1);
            s2 += __expf(leaky(alv.z + arv.z) - m2);
            s3 += __expf(leaky(alv.w + arv.w) - m3);
        }
#pragma unroll
        for (int off = 1; off < 64; off <<= 1) {
            s0 += __shfl_xor(s0, off, 64);
            s1 += __shfl_xor(s1, off, 64);
            s2 += __shfl_xor(s2, off, 64);
            s3 += __shfl_xor(s3, off, 64);
        }
        float mh = (h == 0) ? m0 : (h == 1) ? m1 : (h == 2) ? m2 : m3;
        float sh = (h == 0) ? s0 : (h == 1) ? s1 : (h == 2) ? s2 : s3;
        float arh = (h == 0) ? arv.x : (h == 1) ? arv.y : (h == 2) ? arv.z : arv.w;
        float inv = 1.f / (sh + 1e-16f);
        for (int b2 = rs; b2 < re; b2 += 8) {
            int es = b2 + slot;
            if (es < re) {
                int sv = sorted_src[es];
                const float4 alv = *(const float4*)(al1 + sv * 4);
                float av = (h == 0) ? alv.x : (h == 1) ? alv.y : (h == 2) ? alv.z : alv.w;
                float a = __expf(leaky(av + arh) - mh) * inv;
                const uint4 p = *(const uint4*)(xb + (size_t)sv * D1 + sub * 8);
                acc[0] += bflo(p.x) * a; acc[1] += bfhi(p.x) * a;
                acc[2] += bflo(p.y) * a; acc[3] += bfhi(p.y) * a;
                acc[4] += bflo(p.z) * a; acc[5] += bfhi(p.z) * a;
                acc[6] += bflo(p.w) * a; acc[7] += bfhi(p.w) * a;
            }
        }
    }
    // reduce across the 8 slots (lanes with same sub)
#pragma unroll
    for (int off = 8; off < 64; off <<= 1) {
#pragma unroll
        for (int j = 0; j < 8; j++) acc[j] += __shfl_xor(acc[j], off, 64);
    }
    if (slot == 0) {
        float* p = acc1 + (size_t)d * D1 + sub * 8;
        float4 r0 = *(float4*)p;
        float4 r1 = *((float4*)p + 1);
        r0.x += acc[0]; r0.y += acc[1]; r0.z += acc[2]; r0.w += acc[3];
        r1.x += acc[4]; r1.y += acc[5]; r1.z += acc[6]; r1.w += acc[7];
        // fused ELU
        r0.x = r0.x > 0.f ? r0.x : (__expf(r0.x) - 1.f);
        r0.y = r0.y > 0.f ? r0.y : (__expf(r0.y) - 1.f);
        r0.z = r0.z > 0.f ? r0.z : (__expf(r0.z) - 1.f);
        r0.w = r0.w > 0.f ? r0.w : (__expf(r0.w) - 1.f);
        r1.x = r1.x > 0.f ? r1.x : (__expf(r1.x) - 1.f);
        r1.y = r1.y > 0.f ? r1.y : (__expf(r1.y) - 1.f);
        r1.z = r1.z > 0.f ? r1.z : (__expf(r1.z) - 1.f);
        r1.w = r1.w > 0.f ? r1.w : (__expf(r1.w) - 1.f);
        *(float4*)p = r0;
        *((float4*)p + 1) = r1;
    }
}

// ================= Layer 2 node phase =================
// 64 nodes per 256-thread block (4 waves x 16 nodes); W2 L1/L2-resident.
#define NPB2 64
__global__ __launch_bounds__(256) void node2_kernel(const float* __restrict__ h,
                             const float* __restrict__ W2,
                             const float* __restrict__ attl2,
                             const float* __restrict__ attr2,
                             const float* __restrict__ b2,
                             __hip_bfloat16* __restrict__ xlin2b,
                             float* __restrict__ out,
                             float* __restrict__ al2,
                             float* __restrict__ ar2) {
    int base = blockIdx.x * NPB2;
    int t = threadIdx.x;
    __shared__ float hs[NPB2][D1];   // 16KB
    for (int i = t; i < NPB2 * D1; i += 256) {
        int n = i >> 6, k = i & 63;
        int node = base + n;
        hs[n][k] = (node < NN) ? h[(size_t)node * D1 + k] : 0.f;
    }
    __syncthreads();
    int wave = t >> 6, lane = t & 63;
    int nb = wave * 16;
    float acc[16];
#pragma unroll
    for (int n = 0; n < 16; n++) acc[n] = 0.f;
    for (int k = 0; k < D1; k += 4) {
        float w0 = W2[(k + 0) * OUT_DIM + lane];
        float w1 = W2[(k + 1) * OUT_DIM + lane];
        float w2 = W2[(k + 2) * OUT_DIM + lane];
        float w3 = W2[(k + 3) * OUT_DIM + lane];
#pragma unroll
        for (int n = 0; n < 16; n++) {
            const float4 h4 = *(const float4*)&hs[nb + n][k];
            acc[n] += h4.x * w0 + h4.y * w1 + h4.z * w2 + h4.w * w3;
        }
    }
    float bl = attl2[lane], br = attr2[lane], bv = b2[lane];
#pragma unroll
    for (int n = 0; n < 16; n++) {
        int node = base + nb + n;
        if (node < NN) {
            xlin2b[(size_t)node * OUT_DIM + lane] = __float2bfloat16(acc[n]);
            out[(size_t)node * OUT_DIM + lane] = acc[n] + bv;
        }
        float pl = acc[n] * bl, pr = acc[n] * br;
#pragma unroll
        for (int off = 32; off > 0; off >>= 1) {
            pl += __shfl_down(pl, off, 64);
            pr += __shfl_down(pr, off, 64);
        }
        if (lane == 0 && node < NN) { al2[node] = pl; ar2[node] = pr; }
    }
}

// ================= Fused aggregation, layer 2 (H=1, C=64) =================
__global__ __launch_bounds__(256) void agg2_kernel(
        const int* __restrict__ sorted_src, const int* __restrict__ row_ptr,
        const int* __restrict__ counts,
        const float* __restrict__ al2, const float* __restrict__ ar2,
        const __hip_bfloat16* __restrict__ xlin2b, float* __restrict__ out) {
    __shared__ int   s_srcs[4][64];
    __shared__ float s_alpha[4][64];
    int w = threadIdx.x >> 6;
    int d = blockIdx.x * 4 + w;
    if (d >= NN) return;
    int lane = threadIdx.x & 63;
    int rs = row_ptr[d];
    int deg = counts[d];
    int re = rs + deg;
    float ard = ar2[d];
    int slot = lane >> 3;
    int sub  = lane & 7;
    float acc[8];
#pragma unroll
    for (int j = 0; j < 8; j++) acc[j] = 0.f;
    const unsigned short* xb = (const unsigned short*)xlin2b;

    if (deg <= 64) {
        int e = rs + lane;
        bool act = e < re;
        float l = -1e30f;
        int s = 0;
        if (act) {
            s = sorted_src[e];
            l = leaky(al2[s] + ard);
        }
        float m = l;
#pragma unroll
        for (int off = 1; off < 64; off <<= 1) m = fmaxf(m, __shfl_xor(m, off, 64));
        float ev = act ? __expf(l - m) : 0.f;
        float ss = ev;
#pragma unroll
        for (int off = 1; off < 64; off <<= 1) ss += __shfl_xor(ss, off, 64);
        if (act) {
            s_srcs[w][lane] = s;
            s_alpha[w][lane] = ev / (ss + 1e-16f);
        }
        for (int b2 = rs; b2 < re; b2 += 8) {
            int es = b2 + slot;
            if (es < re) {
                int idx = es - rs;
                int sv = s_srcs[w][idx];
                float a = s_alpha[w][idx];
                const uint4 p = *(const uint4*)(xb + (size_t)sv * OUT_DIM + sub * 8);
                acc[0] += bflo(p.x) * a; acc[1] += bfhi(p.x) * a;
                acc[2] += bflo(p.y) * a; acc[3] += bfhi(p.y) * a;
                acc[4] += bflo(p.z) * a; acc[5] += bfhi(p.z) * a;
                acc[6] += bflo(p.w) * a; acc[7] += bfhi(p.w) * a;
            }
        }
    } else {
        float m = -1e30f;
        for (int e = rs + lane; e < re; e += 64) {
            int s = sorted_src[e];
            m = fmaxf(m, leaky(al2[s] + ard));
        }
#pragma unroll
        for (int off = 1; off < 64; off <<= 1) m = fmaxf(m, __shfl_xor(m, off, 64));
        float ss = 0.f;
        for (int e = rs + lane; e < re; e += 64) {
            int s = sorted_src[e];
            ss += __expf(leaky(al2[s] + ard) - m);
        }
#pragma unroll
        for (int off = 1; off < 64; off <<= 1) ss += __shfl_xor(ss, off, 64);
        float inv = 1.f / (ss + 1e-16f);
        for (int b2 = rs; b2 < re; b2 += 8) {
            int es = b2 + slot;
            if (es < re) {
                int sv = sorted_src[es];
                float a = __expf(leaky(al2[sv] + ard) - m) * inv;
                const uint4 p = *(const uint4*)(xb + (size_t)sv * OUT_DIM + sub * 8);
                acc[0] += bflo(p.x) * a; acc[1] += bfhi(p.x) * a;
                acc[2] += bflo(p.y) * a; acc[3] += bfhi(p.y) * a;
                acc[4] += bflo(p.z) * a; acc[5] += bfhi(p.z) * a;
                acc[6] += bflo(p.w) * a; acc[7] += bfhi(p.w) * a;
            }
        }
    }
#pragma unroll
    for (int off = 8; off < 64; off <<= 1) {
#pragma unroll
        for (int j = 0; j < 8; j++) acc[j] += __shfl_xor(acc[j], off, 64);
    }
    if (slot == 0) {
        float* p = out + (size_t)d * OUT_DIM + sub * 8;
        float4 r0 = *(float4*)p;
        float4 r1 = *((float4*)p + 1);
        r0.x += acc[0]; r0.y += acc[1]; r0.z += acc[2]; r0.w += acc[3];
        r1.x += acc[4]; r1.y += acc[5]; r1.z += acc[6]; r1.w += acc[7];
        *(float4*)p = r0;
        *((float4*)p + 1) = r1;
    }
}

extern "C" void kernel_launch(void* const* d_in, const int* in_sizes, int n_in,
                              void* d_out, int out_size, void* d_ws, size_t ws_size,
                              hipStream_t stream) {
    const float* x     = (const float*)d_in[0];
    const int*   eidx  = (const int*)d_in[1];
    const float* W1    = (const float*)d_in[2];
    const float* attl1 = (const float*)d_in[3];
    const float* attr1 = (const float*)d_in[4];
    const float* resW1 = (const float*)d_in[5];
    const float* b1    = (const float*)d_in[6];
    const float* W2    = (const float*)d_in[7];
    const float* attl2 = (const float*)d_in[8];
    const float* attr2 = (const float*)d_in[9];
    const float* b2    = (const float*)d_in[10];

    const int* src = eidx;
    const int* dst = eidx + EE;

    // workspace layout (bf16 region first; N*64*2B = 12.8MB, 16B-aligned after)
    __hip_bfloat16* xlin1b = (__hip_bfloat16*)d_ws;            // N*64 bf16 (reused as xlin2b)
    float* acc1  = (float*)(xlin1b + (size_t)NN * D1);         // N*64 f32
    float* al1   = acc1 + (size_t)NN * D1;                     // N*4
    float* ar1   = al1 + (size_t)NN * HEADS;                   // N*4
    float* al2   = ar1 + (size_t)NN * HEADS;                   // N
    float* ar2   = al2 + NN;                                   // N
    int* counts        = (int*)(ar2 + NN);                     // N
    int* row_ptr       = counts + NN;                          // N
    int* bucket_counts = row_ptr + NN;                         // 512
    int* bucket_ptr    = bucket_counts + 512;                  // 512
    int* bucket_cursor = bucket_ptr + 512;                     // 512
    int* sorted_src    = bucket_cursor + 512;                  // E
    unsigned* binned = (unsigned*)acc1;       // alias: dead before node1 writes acc1
    __hip_bfloat16* xlin2b = xlin1b;          // alias: xlin1b dead after agg1

    float* out = (float*)d_out;

    // ---- CSR build ----
    zero_buckets<<<1, 512, 0, stream>>>(bucket_counts);
    coarse_hist<<<BINA_BLOCKS, 256, 0, stream>>>(dst, bucket_counts);
    coarse_scan<<<1, 512, 0, stream>>>(bucket_counts, bucket_ptr, bucket_cursor);
    binA_kernel<<<BINA_BLOCKS, 256, 0, stream>>>(src, dst, bucket_cursor, binned);
    binB_kernel<<<NB, 256, 0, stream>>>(binned, bucket_ptr, bucket_counts,
                                        row_ptr, counts, sorted_src);

    // ---- layer 1 ----
    node1_kernel<<<NN / NPB1, 128, 0, stream>>>(x, W1, resW1, attl1, attr1, b1,
                                                xlin1b, acc1, al1, ar1);
    agg1_kernel<<<(NN + 3) / 4, 256, 0, stream>>>(sorted_src, row_ptr, counts,
                                                  al1, ar1, xlin1b, acc1);

    // ---- layer 2 ----
    node2_kernel<<<(NN + NPB2 - 1) / NPB2, 256, 0, stream>>>(acc1, W2, attl2, attr2, b2,
                                                             xlin2b, out, al2, ar2);
    agg2_kernel<<<(NN + 3) / 4, 256, 0, stream>>>(sorted_src, row_ptr, counts,
                                                  al2, ar2, xlin2b, out);
}